// Round 1
// baseline (491.887 us; speedup 1.0000x reference)
//
#include <hip/hip_runtime.h>

// TGNN encoder v2 — latency-bound fix.
// B=1024, N=200, DN=DT=128, M=384.
// Grid: 512 blocks x 512 threads; each block handles 2 batch rows (waves 0-3 -> row0, 4-7 -> row1).
// Main loop: 2 keys/iter via float4 loads (half-wave per key), depth-2 prefetch, full unroll.
// GEMVs use pre-transposed weights (prep kernel -> __device__ globals): per-thread output,
// coalesced weight streams, LDS-broadcast x, no cross-lane reduces.
// d_out layout: [ out (1024*128 f32) | attn_w (1024*200 f32) ]

constexpr int B_   = 1024;
constexpr int N_   = 200;
constexpr int DN_  = 128;
constexpr int DT_  = 128;
constexpr int M_   = 384;       // DN + DN + DT
constexpr int BDIM = 512;       // 8 waves
constexpr int ROWS = 2;         // batch rows per block
constexpr int WPR  = 4;         // waves per row
constexpr int NPW  = N_ / WPR;  // 50 keys per wave
constexpr int PAIRS = NPW / 2;  // 25 pair-iterations

__device__ float g_fcT[M_ * M_];                 // [j][i] = fc_w[i][j]
__device__ float g_w1T[(M_ + DN_) * (2 * DN_)];  // [j][i] = w1[i][j], j<512, i<256
__device__ float g_w2T[(2 * DN_) * DN_];         // [j][i] = w2[i][j], j<256, i<128

__device__ __forceinline__ float half_sum(float v) {   // sum+broadcast within each 32-lane half
#pragma unroll
    for (int off = 16; off > 0; off >>= 1) v += __shfl_xor(v, off, 64);
    return v;
}
__device__ __forceinline__ float wave_sum(float v) {   // full 64-lane sum+broadcast
#pragma unroll
    for (int off = 32; off > 0; off >>= 1) v += __shfl_xor(v, off, 64);
    return v;
}

struct KP { float4 a, e, t; };

__global__ void transpose_weights(const float* __restrict__ fc_w,
                                  const float* __restrict__ w1,
                                  const float* __restrict__ w2) {
    const int stride = gridDim.x * blockDim.x;
    for (int idx = blockIdx.x * blockDim.x + threadIdx.x; idx < M_ * M_; idx += stride) {
        const int j = idx / M_, i = idx - j * M_;
        g_fcT[idx] = fc_w[i * M_ + j];
    }
    for (int idx = blockIdx.x * blockDim.x + threadIdx.x; idx < (M_ + DN_) * (2 * DN_); idx += stride) {
        const int j = idx >> 8, i = idx & 255;
        g_w1T[idx] = w1[i * (M_ + DN_) + j];
    }
    for (int idx = blockIdx.x * blockDim.x + threadIdx.x; idx < (2 * DN_) * DN_; idx += stride) {
        const int j = idx >> 7, i = idx & 127;
        g_w2T[idx] = w2[i * (2 * DN_) + j];
    }
}

__global__ __launch_bounds__(BDIM, 4) void tgnn_kernel(
    const float* __restrict__ src,      // (B, DN)
    const float* __restrict__ src_t,    // (B, 1, DT)
    const float* __restrict__ seq,      // (B, N, DN)
    const float* __restrict__ seq_t,    // (B, N, DT)
    const float* __restrict__ seq_e,    // (B, N, DN)
    const int*   __restrict__ mask,     // (B, N) int32 (bool)
    const float* __restrict__ shared_attn, // (2M,)
    const float* __restrict__ ln_g,     // (M,)
    const float* __restrict__ ln_b,     // (M,)
    float* __restrict__ out,            // (B, DN)
    float* __restrict__ attn_out)       // (B, N)
{
    const int blk  = blockIdx.x;
    const int tid  = threadIdx.x;
    const int wave = tid >> 6;       // 0..7
    const int lane = tid & 63;
    const int row  = wave >> 2;      // 0/1: which batch row in this block
    const int wir  = wave & 3;       // wave index within row
    const int b    = blk * ROWS + row;
    const int half = lane >> 5;      // 0/1: key within pair
    const int sub  = lane & 31;
    const int c0   = 4 * sub;        // element base within a 128-slice

    __shared__ float s_p[ROWS][N_];         // unnormalized exp(score)
    __shared__ float s_q[ROWS][M_];         // q = [src, 0, src_t]
    __shared__ float s_oa[8][M_];           // per-wave weighted-sum accumulators
    __shared__ float s_x[ROWS][M_];         // normalized attn @ k
    __shared__ float s_y[ROWS][M_ + DN_];   // LN output ++ src
    __shared__ float s_h[ROWS][2 * DN_];    // relu(x @ w1.T)
    __shared__ int   s_mask[ROWS][N_];
    __shared__ float s_red[ROWS][8];

    // ---- stage q and mask for both rows (coalesced) ----
    for (int idx = tid; idx < ROWS * M_; idx += BDIM) {
        const int r = idx / M_, d = idx - r * M_;
        const int bb = blk * ROWS + r;
        float v = (d < DN_) ? src[bb * DN_ + d]
                            : (d < 2 * DN_ ? 0.0f : src_t[bb * DT_ + (d - 2 * DN_)]);
        s_q[r][d] = v;
    }
    for (int idx = tid; idx < ROWS * N_; idx += BDIM) {
        const int r = idx / N_, n = idx - r * N_;
        s_mask[r][n] = mask[(blk * ROWS + r) * N_ + n];
    }

    // ---- per-lane weight fragments (global, L2-hot; same for both halves) ----
    const float* wq = shared_attn;
    const float* wk = shared_attn + M_;
    const float4 wkA = *(const float4*)&wk[c0];
    const float4 wkE = *(const float4*)&wk[DN_ + c0];
    const float4 wkT = *(const float4*)&wk[2 * DN_ + c0];
    const float4 wqA = *(const float4*)&wq[c0];
    const float4 wqT = *(const float4*)&wq[2 * DN_ + c0];

    __syncthreads();

    // ---- q-side score (constant over n) ----
    const float4 qa = *(const float4*)&s_q[row][c0];
    const float4 qt = *(const float4*)&s_q[row][2 * DN_ + c0];
    float qp = qa.x * wqA.x + qa.y * wqA.y + qa.z * wqA.z + qa.w * wqA.w
             + qt.x * wqT.x + qt.y * wqT.y + qt.z * wqT.z + qt.w * wqT.w;
    const float qdot = half_sum(qp);

    // ---- fused score + online weighted-sum: 2 keys/iter, depth-2 prefetch ----
    const long krow0 = (long)b * N_ + wir * NPW + half;
    const float* pA = seq   + krow0 * DN_ + c0;
    const float* pE = seq_e + krow0 * DN_ + c0;
    const float* pT = seq_t + krow0 * DT_ + c0;
    auto ldp = [&](int it) {
        KP k;
        const long off = (long)(2 * it) * DN_;
        k.a = *(const float4*)(pA + off);
        k.e = *(const float4*)(pE + off);
        k.t = *(const float4*)(pT + off);
        return k;
    };

    float4 oA = make_float4(0.f, 0.f, 0.f, 0.f);
    float4 oE = oA, oT = oA;
    float lsum = 0.f;
    KP k0 = ldp(0);
    KP k1 = ldp(1);
#pragma unroll
    for (int it = 0; it < PAIRS; ++it) {
        int pf = it + 2; if (pf > PAIRS - 1) pf = PAIRS - 1;
        KP k2 = ldp(pf);   // keep loads in flight under the reduce chain

        float part = k0.a.x * wkA.x + k0.a.y * wkA.y + k0.a.z * wkA.z + k0.a.w * wkA.w
                   + k0.e.x * wkE.x + k0.e.y * wkE.y + k0.e.z * wkE.z + k0.e.w * wkE.w
                   + k0.t.x * wkT.x + k0.t.y * wkT.y + k0.t.z * wkT.z + k0.t.w * wkT.w;
        part = half_sum(part);                      // per-half sum, broadcast
        const int n = wir * NPW + 2 * it + half;
        const float p = s_mask[row][n] ? 0.0f : __expf(part + qdot);
        if (sub == 0) { s_p[row][n] = p; lsum += p; }
        oA.x += p * k0.a.x; oA.y += p * k0.a.y; oA.z += p * k0.a.z; oA.w += p * k0.a.w;
        oE.x += p * k0.e.x; oE.y += p * k0.e.y; oE.z += p * k0.e.z; oE.w += p * k0.e.w;
        oT.x += p * k0.t.x; oT.y += p * k0.t.y; oT.z += p * k0.t.z; oT.w += p * k0.t.w;
        k0 = k1; k1 = k2;
    }

    // ---- combine the two halves of the wave ----
    oA.x += __shfl_xor(oA.x, 32, 64); oA.y += __shfl_xor(oA.y, 32, 64);
    oA.z += __shfl_xor(oA.z, 32, 64); oA.w += __shfl_xor(oA.w, 32, 64);
    oE.x += __shfl_xor(oE.x, 32, 64); oE.y += __shfl_xor(oE.y, 32, 64);
    oE.z += __shfl_xor(oE.z, 32, 64); oE.w += __shfl_xor(oE.w, 32, 64);
    oT.x += __shfl_xor(oT.x, 32, 64); oT.y += __shfl_xor(oT.y, 32, 64);
    oT.z += __shfl_xor(oT.z, 32, 64); oT.w += __shfl_xor(oT.w, 32, 64);
    lsum += __shfl_xor(lsum, 32, 64);
    if (lane == 0) s_red[row][wir] = lsum;
    if (half == 0) {
        *(float4*)&s_oa[wave][c0]            = oA;
        *(float4*)&s_oa[wave][DN_ + c0]      = oE;
        *(float4*)&s_oa[wave][2 * DN_ + c0]  = oT;
    }
    __syncthreads();

    // ---- normalize: attn output vector + attention weights ----
    for (int idx = tid; idx < ROWS * M_; idx += BDIM) {
        const int r = idx / M_, d = idx - r * M_;
        const float Z = s_red[r][0] + s_red[r][1] + s_red[r][2] + s_red[r][3];
        const float invZ = 1.0f / Z;
        s_x[r][d] = (s_oa[4 * r + 0][d] + s_oa[4 * r + 1][d] +
                     s_oa[4 * r + 2][d] + s_oa[4 * r + 3][d]) * invZ;
    }
    for (int idx = tid; idx < ROWS * N_; idx += BDIM) {
        const int r = idx / N_, n = idx - r * N_;
        const float Z = s_red[r][0] + s_red[r][1] + s_red[r][2] + s_red[r][3];
        attn_out[(blk * ROWS + r) * N_ + n] = s_p[r][n] * (1.0f / Z);
    }
    __syncthreads();

    // ---- fc: out2[r][i] = dot(x[r], fc_w[i,:]) + q[r][i]; coalesced W^T stream ----
    if (tid < M_) {
        float acc0 = 0.f, acc1 = 0.f;
#pragma unroll 8
        for (int j = 0; j < M_; ++j) {
            const float w = g_fcT[j * M_ + tid];
            acc0 += s_x[0][j] * w;       // LDS broadcast
            acc1 += s_x[1][j] * w;
        }
        s_y[0][tid] = acc0 + s_q[0][tid];
        s_y[1][tid] = acc1 + s_q[1][tid];
    }
    __syncthreads();

    // ---- layer norm over M (per row: 4 waves) ----
    {
        float ls = 0.f, lq = 0.f;
        for (int j = 64 * wir + lane; j < M_; j += 256) {
            const float v = s_y[row][j];
            ls += v; lq += v * v;
        }
        ls = wave_sum(ls); lq = wave_sum(lq);
        if (lane == 0) { s_red[row][wir] = ls; s_red[row][4 + wir] = lq; }
    }
    __syncthreads();
    for (int idx = tid; idx < ROWS * M_; idx += BDIM) {
        const int r = idx / M_, j = idx - r * M_;
        const float mean = (s_red[r][0] + s_red[r][1] + s_red[r][2] + s_red[r][3]) * (1.0f / M_);
        const float msq  = (s_red[r][4] + s_red[r][5] + s_red[r][6] + s_red[r][7]) * (1.0f / M_);
        const float rstd = rsqrtf(msq - mean * mean + 1e-5f);
        s_y[r][j] = (s_y[r][j] - mean) * rstd * ln_g[j] + ln_b[j];
    }
    for (int idx = tid; idx < ROWS * DN_; idx += BDIM) {
        const int r = idx >> 7, d = idx & 127;
        s_y[r][M_ + d] = s_q[r][d];       // concat src
    }
    __syncthreads();

    // ---- agg fc1: h[r][i] = relu(dot(x512[r], w1[i,:])); thread-per-output ----
    {
        const int r = tid >> 8, i = tid & 255;
        float acc = 0.f;
#pragma unroll 8
        for (int j = 0; j < M_ + DN_; ++j)
            acc += s_y[r][j] * g_w1T[j * 256 + i];
        s_h[r][i] = fmaxf(acc, 0.0f);
    }
    __syncthreads();

    // ---- agg fc2: out[r][i] = dot(h[r], w2[i,:]) ----
    if (tid < 256) {
        const int r = tid >> 7, i = tid & 127;
        float acc = 0.f;
#pragma unroll 8
        for (int j = 0; j < 2 * DN_; ++j)
            acc += s_h[r][j] * g_w2T[j * 128 + i];
        out[(blk * ROWS + r) * DN_ + i] = acc;
    }
}

extern "C" void kernel_launch(void* const* d_in, const int* in_sizes, int n_in,
                              void* d_out, int out_size, void* d_ws, size_t ws_size,
                              hipStream_t stream) {
    const float* src         = (const float*)d_in[0];
    const float* src_t       = (const float*)d_in[1];
    const float* seq         = (const float*)d_in[2];
    const float* seq_t       = (const float*)d_in[3];
    const float* seq_e       = (const float*)d_in[4];
    const int*   mask        = (const int*)  d_in[5];
    const float* shared_attn = (const float*)d_in[6];
    const float* fc_w        = (const float*)d_in[7];
    const float* ln_g        = (const float*)d_in[8];
    const float* ln_b        = (const float*)d_in[9];
    const float* w1          = (const float*)d_in[10];
    const float* w2          = (const float*)d_in[11];

    float* outp     = (float*)d_out;             // (B, DN)
    float* attn_out = (float*)d_out + B_ * DN_;  // (B, N)

    transpose_weights<<<256, 256, 0, stream>>>(fc_w, w1, w2);
    tgnn_kernel<<<B_ / ROWS, BDIM, 0, stream>>>(src, src_t, seq, seq_t, seq_e, mask,
                                                shared_attn, ln_g, ln_b, outp, attn_out);
}

// Round 2
// 485.991 us; speedup vs baseline: 1.0121x; 1.0121x over previous
//
#include <hip/hip_runtime.h>

// TGNN encoder v3 — v2 structure with the spill eliminated.
// B=1024, N=200, DN=DT=128, M=384.
// Grid: 512 blocks x 512 threads; each block handles 2 batch rows (waves 0-3 -> row0, 4-7 -> row1).
// Main loop: 2 keys/iter via float4 loads (half-wave per key), plain indexed loop + unroll-4
// (compiler hoists the window's 12 float4 loads; no hand rotation -> no spill).
// Register tier pinned at 4 waves/EU (cap 128 VGPR) via amdgpu_waves_per_eu(4,4):
// v2's allocator chose the 64-reg tier and spilled ~1KB/thread (WRITE_SIZE 247MB).
// GEMVs use pre-transposed weights (prep kernel -> __device__ globals): per-thread output,
// coalesced weight streams, LDS-broadcast x, no cross-lane reduces.
// d_out layout: [ out (1024*128 f32) | attn_w (1024*200 f32) ]

constexpr int B_   = 1024;
constexpr int N_   = 200;
constexpr int DN_  = 128;
constexpr int DT_  = 128;
constexpr int M_   = 384;       // DN + DN + DT
constexpr int BDIM = 512;       // 8 waves
constexpr int ROWS = 2;         // batch rows per block
constexpr int WPR  = 4;         // waves per row
constexpr int NPW  = N_ / WPR;  // 50 keys per wave
constexpr int PAIRS = NPW / 2;  // 25 pair-iterations

__device__ float g_fcT[M_ * M_];                 // [j][i] = fc_w[i][j]
__device__ float g_w1T[(M_ + DN_) * (2 * DN_)];  // [j][i] = w1[i][j], j<512, i<256
__device__ float g_w2T[(2 * DN_) * DN_];         // [j][i] = w2[i][j], j<256, i<128

__device__ __forceinline__ float half_sum(float v) {   // sum+broadcast within each 32-lane half
#pragma unroll
    for (int off = 16; off > 0; off >>= 1) v += __shfl_xor(v, off, 64);
    return v;
}
__device__ __forceinline__ float wave_sum(float v) {   // full 64-lane sum+broadcast
#pragma unroll
    for (int off = 32; off > 0; off >>= 1) v += __shfl_xor(v, off, 64);
    return v;
}

__global__ void transpose_weights(const float* __restrict__ fc_w,
                                  const float* __restrict__ w1,
                                  const float* __restrict__ w2) {
    const int stride = gridDim.x * blockDim.x;
    for (int idx = blockIdx.x * blockDim.x + threadIdx.x; idx < M_ * M_; idx += stride) {
        const int j = idx / M_, i = idx - j * M_;
        g_fcT[idx] = fc_w[i * M_ + j];
    }
    for (int idx = blockIdx.x * blockDim.x + threadIdx.x; idx < (M_ + DN_) * (2 * DN_); idx += stride) {
        const int j = idx >> 8, i = idx & 255;
        g_w1T[idx] = w1[i * (M_ + DN_) + j];
    }
    for (int idx = blockIdx.x * blockDim.x + threadIdx.x; idx < (2 * DN_) * DN_; idx += stride) {
        const int j = idx >> 7, i = idx & 127;
        g_w2T[idx] = w2[i * (2 * DN_) + j];
    }
}

__global__ __launch_bounds__(BDIM) __attribute__((amdgpu_waves_per_eu(4, 4)))
void tgnn_kernel(
    const float* __restrict__ src,      // (B, DN)
    const float* __restrict__ src_t,    // (B, 1, DT)
    const float* __restrict__ seq,      // (B, N, DN)
    const float* __restrict__ seq_t,    // (B, N, DT)
    const float* __restrict__ seq_e,    // (B, N, DN)
    const int*   __restrict__ mask,     // (B, N) int32 (bool)
    const float* __restrict__ shared_attn, // (2M,)
    const float* __restrict__ ln_g,     // (M,)
    const float* __restrict__ ln_b,     // (M,)
    float* __restrict__ out,            // (B, DN)
    float* __restrict__ attn_out)       // (B, N)
{
    const int blk  = blockIdx.x;
    const int tid  = threadIdx.x;
    const int wave = tid >> 6;       // 0..7
    const int lane = tid & 63;
    const int row  = wave >> 2;      // 0/1: which batch row in this block
    const int wir  = wave & 3;       // wave index within row
    const int b    = blk * ROWS + row;
    const int half = lane >> 5;      // 0/1: key within pair
    const int sub  = lane & 31;
    const int c0   = 4 * sub;        // element base within a 128-slice

    __shared__ float s_p[ROWS][N_];         // unnormalized exp(score)
    __shared__ float s_q[ROWS][M_];         // q = [src, 0, src_t]
    __shared__ float s_oa[8][M_];           // per-wave weighted-sum accumulators
    __shared__ float s_x[ROWS][M_];         // normalized attn @ k
    __shared__ float s_y[ROWS][M_ + DN_];   // LN output ++ src
    __shared__ float s_h[ROWS][2 * DN_];    // relu(x @ w1.T)
    __shared__ int   s_mask[ROWS][N_];
    __shared__ float s_red[ROWS][8];

    // ---- stage q and mask for both rows (coalesced) ----
    for (int idx = tid; idx < ROWS * M_; idx += BDIM) {
        const int r = idx / M_, d = idx - r * M_;
        const int bb = blk * ROWS + r;
        float v = (d < DN_) ? src[bb * DN_ + d]
                            : (d < 2 * DN_ ? 0.0f : src_t[bb * DT_ + (d - 2 * DN_)]);
        s_q[r][d] = v;
    }
    for (int idx = tid; idx < ROWS * N_; idx += BDIM) {
        const int r = idx / N_, n = idx - r * N_;
        s_mask[r][n] = mask[(blk * ROWS + r) * N_ + n];
    }

    // ---- per-lane weight fragments (global, L2-hot; same for both halves) ----
    const float* wq = shared_attn;
    const float* wk = shared_attn + M_;
    const float4 wkA = *(const float4*)&wk[c0];
    const float4 wkE = *(const float4*)&wk[DN_ + c0];
    const float4 wkT = *(const float4*)&wk[2 * DN_ + c0];
    const float4 wqA = *(const float4*)&wq[c0];
    const float4 wqT = *(const float4*)&wq[2 * DN_ + c0];

    __syncthreads();

    // ---- q-side score (constant over n) ----
    const float4 qa = *(const float4*)&s_q[row][c0];
    const float4 qt = *(const float4*)&s_q[row][2 * DN_ + c0];
    float qp = qa.x * wqA.x + qa.y * wqA.y + qa.z * wqA.z + qa.w * wqA.w
             + qt.x * wqT.x + qt.y * wqT.y + qt.z * wqT.z + qt.w * wqT.w;
    const float qdot = half_sum(qp);

    // ---- fused score + online weighted-sum: 2 keys/iter (one per half-wave) ----
    const int  nb    = wir * NPW + half;          // this half's first key
    const long krow0 = (long)b * N_ + nb;
    const float* pA = seq   + krow0 * DN_ + c0;
    const float* pE = seq_e + krow0 * DN_ + c0;
    const float* pT = seq_t + krow0 * DT_ + c0;
    constexpr int STRIDE = 2 * DN_;               // floats per pair-iteration

    float4 oA = make_float4(0.f, 0.f, 0.f, 0.f);
    float4 oE = oA, oT = oA;
    float lsum = 0.f;
#pragma unroll 4
    for (int it = 0; it < PAIRS; ++it) {
        const float4 a = *(const float4*)(pA + (long)it * STRIDE);
        const float4 e = *(const float4*)(pE + (long)it * STRIDE);
        const float4 t = *(const float4*)(pT + (long)it * STRIDE);
        float part = a.x * wkA.x + a.y * wkA.y + a.z * wkA.z + a.w * wkA.w
                   + e.x * wkE.x + e.y * wkE.y + e.z * wkE.z + e.w * wkE.w
                   + t.x * wkT.x + t.y * wkT.y + t.z * wkT.z + t.w * wkT.w;
        part = half_sum(part);                    // per-half sum, broadcast
        const int n = nb + 2 * it;
        const float p = s_mask[row][n] ? 0.0f : __expf(part + qdot);
        if (sub == 0) s_p[row][n] = p;
        lsum += p;                                // uniform across the half
        oA.x += p * a.x; oA.y += p * a.y; oA.z += p * a.z; oA.w += p * a.w;
        oE.x += p * e.x; oE.y += p * e.y; oE.z += p * e.z; oE.w += p * e.w;
        oT.x += p * t.x; oT.y += p * t.y; oT.z += p * t.z; oT.w += p * t.w;
    }

    // ---- combine the two halves of the wave ----
    oA.x += __shfl_xor(oA.x, 32, 64); oA.y += __shfl_xor(oA.y, 32, 64);
    oA.z += __shfl_xor(oA.z, 32, 64); oA.w += __shfl_xor(oA.w, 32, 64);
    oE.x += __shfl_xor(oE.x, 32, 64); oE.y += __shfl_xor(oE.y, 32, 64);
    oE.z += __shfl_xor(oE.z, 32, 64); oE.w += __shfl_xor(oE.w, 32, 64);
    oT.x += __shfl_xor(oT.x, 32, 64); oT.y += __shfl_xor(oT.y, 32, 64);
    oT.z += __shfl_xor(oT.z, 32, 64); oT.w += __shfl_xor(oT.w, 32, 64);
    lsum += __shfl_xor(lsum, 32, 64);
    if (lane == 0) s_red[row][wir] = lsum;
    if (half == 0) {
        *(float4*)&s_oa[wave][c0]            = oA;
        *(float4*)&s_oa[wave][DN_ + c0]      = oE;
        *(float4*)&s_oa[wave][2 * DN_ + c0]  = oT;
    }
    __syncthreads();

    // ---- normalize: attn output vector + attention weights ----
    for (int idx = tid; idx < ROWS * M_; idx += BDIM) {
        const int r = idx / M_, d = idx - r * M_;
        const float Z = s_red[r][0] + s_red[r][1] + s_red[r][2] + s_red[r][3];
        const float invZ = 1.0f / Z;
        s_x[r][d] = (s_oa[4 * r + 0][d] + s_oa[4 * r + 1][d] +
                     s_oa[4 * r + 2][d] + s_oa[4 * r + 3][d]) * invZ;
    }
    for (int idx = tid; idx < ROWS * N_; idx += BDIM) {
        const int r = idx / N_, n = idx - r * N_;
        const float Z = s_red[r][0] + s_red[r][1] + s_red[r][2] + s_red[r][3];
        attn_out[(blk * ROWS + r) * N_ + n] = s_p[r][n] * (1.0f / Z);
    }
    __syncthreads();

    // ---- fc: out2[r][i] = dot(x[r], fc_w[i,:]) + q[r][i]; coalesced W^T stream ----
    if (tid < M_) {
        float acc0 = 0.f, acc1 = 0.f;
#pragma unroll 8
        for (int j = 0; j < M_; ++j) {
            const float w = g_fcT[j * M_ + tid];
            acc0 += s_x[0][j] * w;       // LDS broadcast
            acc1 += s_x[1][j] * w;
        }
        s_y[0][tid] = acc0 + s_q[0][tid];
        s_y[1][tid] = acc1 + s_q[1][tid];
    }
    __syncthreads();

    // ---- layer norm over M (per row: 4 waves) ----
    {
        float ls = 0.f, lq = 0.f;
        for (int j = 64 * wir + lane; j < M_; j += 256) {
            const float v = s_y[row][j];
            ls += v; lq += v * v;
        }
        ls = wave_sum(ls); lq = wave_sum(lq);
        if (lane == 0) { s_red[row][wir] = ls; s_red[row][4 + wir] = lq; }
    }
    __syncthreads();
    for (int idx = tid; idx < ROWS * M_; idx += BDIM) {
        const int r = idx / M_, j = idx - r * M_;
        const float mean = (s_red[r][0] + s_red[r][1] + s_red[r][2] + s_red[r][3]) * (1.0f / M_);
        const float msq  = (s_red[r][4] + s_red[r][5] + s_red[r][6] + s_red[r][7]) * (1.0f / M_);
        const float rstd = rsqrtf(msq - mean * mean + 1e-5f);
        s_y[r][j] = (s_y[r][j] - mean) * rstd * ln_g[j] + ln_b[j];
    }
    for (int idx = tid; idx < ROWS * DN_; idx += BDIM) {
        const int r = idx >> 7, d = idx & 127;
        s_y[r][M_ + d] = s_q[r][d];       // concat src
    }
    __syncthreads();

    // ---- agg fc1: h[r][i] = relu(dot(x512[r], w1[i,:])); thread-per-output ----
    {
        const int r = tid >> 8, i = tid & 255;
        float acc = 0.f;
#pragma unroll 8
        for (int j = 0; j < M_ + DN_; ++j)
            acc += s_y[r][j] * g_w1T[j * 256 + i];
        s_h[r][i] = fmaxf(acc, 0.0f);
    }
    __syncthreads();

    // ---- agg fc2: out[r][i] = dot(h[r], w2[i,:]) ----
    if (tid < 256) {
        const int r = tid >> 7, i = tid & 127;
        float acc = 0.f;
#pragma unroll 8
        for (int j = 0; j < 2 * DN_; ++j)
            acc += s_h[r][j] * g_w2T[j * 128 + i];
        out[(blk * ROWS + r) * DN_ + i] = acc;
    }
}

extern "C" void kernel_launch(void* const* d_in, const int* in_sizes, int n_in,
                              void* d_out, int out_size, void* d_ws, size_t ws_size,
                              hipStream_t stream) {
    const float* src         = (const float*)d_in[0];
    const float* src_t       = (const float*)d_in[1];
    const float* seq         = (const float*)d_in[2];
    const float* seq_t       = (const float*)d_in[3];
    const float* seq_e       = (const float*)d_in[4];
    const int*   mask        = (const int*)  d_in[5];
    const float* shared_attn = (const float*)d_in[6];
    const float* fc_w        = (const float*)d_in[7];
    const float* ln_g        = (const float*)d_in[8];
    const float* ln_b        = (const float*)d_in[9];
    const float* w1          = (const float*)d_in[10];
    const float* w2          = (const float*)d_in[11];

    float* outp     = (float*)d_out;             // (B, DN)
    float* attn_out = (float*)d_out + B_ * DN_;  // (B, N)

    transpose_weights<<<256, 256, 0, stream>>>(fc_w, w1, w2);
    tgnn_kernel<<<B_ / ROWS, BDIM, 0, stream>>>(src, src_t, seq, seq_t, seq_e, mask,
                                                shared_attn, ln_g, ln_b, outp, attn_out);
}

// Round 3
// 380.580 us; speedup vs baseline: 1.2925x; 1.2770x over previous
//
#include <hip/hip_runtime.h>

// TGNN encoder v4 — kill the spill by construction.
// B=1024, N=200, DN=DT=128, M=384.
// Grid: 512 blocks x 512 threads; each block handles 2 batch rows (waves 0-3 -> row0, 4-7 -> row1).
// Main loop: 2 keys/iter (one per 32-lane half), float4 loads, UNROLL 1 with an
// opaque (asm-clobbered) trip count so the compiler cannot full-unroll or cluster
// loads across iterations. Live set ~46 VGPR < 64-reg tier -> no scratch.
// (v2/v3 post-mortem: demand ~78 vs 64-reg cap -> ~1KB/thread spill churn,
//  WRITE_SIZE 247-259MB vs 1.3MB real output. Allocator ignored waves_per_eu/launch_bounds.)
// All three key tensors share one 32-bit element offset (identical (N,128) layout);
// bases are wave-uniform SGPR pairs.
// GEMVs use pre-transposed weights (prep kernel -> __device__ globals): per-thread output,
// coalesced weight streams, LDS-broadcast x, no cross-lane reduces.
// d_out layout: [ out (1024*128 f32) | attn_w (1024*200 f32) ]

constexpr int B_   = 1024;
constexpr int N_   = 200;
constexpr int DN_  = 128;
constexpr int DT_  = 128;
constexpr int M_   = 384;       // DN + DN + DT
constexpr int BDIM = 512;       // 8 waves
constexpr int ROWS = 2;         // batch rows per block
constexpr int WPR  = 4;         // waves per row
constexpr int NPW  = N_ / WPR;  // 50 keys per wave
constexpr int PAIRS = NPW / 2;  // 25 pair-iterations

__device__ float g_fcT[M_ * M_];                 // [j][i] = fc_w[i][j]
__device__ float g_w1T[(M_ + DN_) * (2 * DN_)];  // [j][i] = w1[i][j], j<512, i<256
__device__ float g_w2T[(2 * DN_) * DN_];         // [j][i] = w2[i][j], j<256, i<128

__device__ __forceinline__ float half_sum(float v) {   // sum+broadcast within each 32-lane half
#pragma unroll
    for (int off = 16; off > 0; off >>= 1) v += __shfl_xor(v, off, 64);
    return v;
}
__device__ __forceinline__ float wave_sum(float v) {   // full 64-lane sum+broadcast
#pragma unroll
    for (int off = 32; off > 0; off >>= 1) v += __shfl_xor(v, off, 64);
    return v;
}

__global__ void transpose_weights(const float* __restrict__ fc_w,
                                  const float* __restrict__ w1,
                                  const float* __restrict__ w2) {
    const int stride = gridDim.x * blockDim.x;
    for (int idx = blockIdx.x * blockDim.x + threadIdx.x; idx < M_ * M_; idx += stride) {
        const int j = idx / M_, i = idx - j * M_;
        g_fcT[idx] = fc_w[i * M_ + j];
    }
    for (int idx = blockIdx.x * blockDim.x + threadIdx.x; idx < (M_ + DN_) * (2 * DN_); idx += stride) {
        const int j = idx >> 8, i = idx & 255;
        g_w1T[idx] = w1[i * (M_ + DN_) + j];
    }
    for (int idx = blockIdx.x * blockDim.x + threadIdx.x; idx < (2 * DN_) * DN_; idx += stride) {
        const int j = idx >> 7, i = idx & 127;
        g_w2T[idx] = w2[i * (2 * DN_) + j];
    }
}

__global__ __launch_bounds__(BDIM)
void tgnn_kernel(
    const float* __restrict__ src,      // (B, DN)
    const float* __restrict__ src_t,    // (B, 1, DT)
    const float* __restrict__ seq,      // (B, N, DN)
    const float* __restrict__ seq_t,    // (B, N, DT)
    const float* __restrict__ seq_e,    // (B, N, DN)
    const int*   __restrict__ mask,     // (B, N) int32 (bool)
    const float* __restrict__ shared_attn, // (2M,)
    const float* __restrict__ ln_g,     // (M,)
    const float* __restrict__ ln_b,     // (M,)
    float* __restrict__ out,            // (B, DN)
    float* __restrict__ attn_out)       // (B, N)
{
    const int blk  = blockIdx.x;
    const int tid  = threadIdx.x;
    const int wave = tid >> 6;       // 0..7
    const int lane = tid & 63;
    const int row  = wave >> 2;      // 0/1: which batch row in this block
    const int wir  = wave & 3;       // wave index within row
    const int b    = blk * ROWS + row;
    const int half = lane >> 5;      // 0/1: key within pair
    const int sub  = lane & 31;
    const int c0   = 4 * sub;        // element base within a 128-slice

    __shared__ float s_p[ROWS][N_];         // unnormalized exp(score)
    __shared__ float s_q[ROWS][M_];         // q = [src, 0, src_t]
    __shared__ float s_oa[8][M_];           // per-wave weighted-sum accumulators
    __shared__ float s_x[ROWS][M_];         // normalized attn @ k
    __shared__ float s_y[ROWS][M_ + DN_];   // LN output ++ src
    __shared__ float s_h[ROWS][2 * DN_];    // relu(x @ w1.T)
    __shared__ int   s_mask[ROWS][N_];
    __shared__ float s_red[ROWS][8];

    // ---- stage q and mask for both rows (coalesced) ----
    for (int idx = tid; idx < ROWS * M_; idx += BDIM) {
        const int r = idx / M_, d = idx - r * M_;
        const int bb = blk * ROWS + r;
        float v = (d < DN_) ? src[bb * DN_ + d]
                            : (d < 2 * DN_ ? 0.0f : src_t[bb * DT_ + (d - 2 * DN_)]);
        s_q[r][d] = v;
    }
    for (int idx = tid; idx < ROWS * N_; idx += BDIM) {
        const int r = idx / N_, n = idx - r * N_;
        s_mask[r][n] = mask[(blk * ROWS + r) * N_ + n];
    }

    // ---- per-lane weight fragments (global, L2-hot; same for both halves) ----
    const float* wq = shared_attn;
    const float* wk = shared_attn + M_;
    const float4 wkA = *(const float4*)&wk[c0];
    const float4 wkE = *(const float4*)&wk[DN_ + c0];
    const float4 wkT = *(const float4*)&wk[2 * DN_ + c0];
    const float4 wqA = *(const float4*)&wq[c0];
    const float4 wqT = *(const float4*)&wq[2 * DN_ + c0];

    __syncthreads();

    // ---- q-side score (constant over n) ----
    const float4 qa = *(const float4*)&s_q[row][c0];
    const float4 qt = *(const float4*)&s_q[row][2 * DN_ + c0];
    float qp = qa.x * wqA.x + qa.y * wqA.y + qa.z * wqA.z + qa.w * wqA.w
             + qt.x * wqT.x + qt.y * wqT.y + qt.z * wqT.z + qt.w * wqT.w;
    const float qdot = half_sum(qp);

    // ---- fused score + online weighted-sum: 2 keys/iter (one per half-wave) ----
    // All three tensors share layout (B, N, 128) -> one 32-bit element offset.
    const int nb = wir * NPW + half;              // this half's first key
    const float* baseA = seq   + (long)b * (N_ * DN_);
    const float* baseE = seq_e + (long)b * (N_ * DN_);
    const float* baseT = seq_t + (long)b * (N_ * DT_);
    int off = nb * DN_ + c0;                      // element offset, < 25600
    int n   = nb;

    float4 oA = make_float4(0.f, 0.f, 0.f, 0.f);
    float4 oE = oA, oT = oA;
    float lsum = 0.f;

    int pairs = PAIRS;
    asm volatile("" : "+s"(pairs));               // opaque bound: no full unroll / cross-iter hoist
#pragma unroll 1
    for (int it = 0; it < pairs; ++it) {
        const float4 a = *(const float4*)(baseA + off);
        const float4 e = *(const float4*)(baseE + off);
        const float4 t = *(const float4*)(baseT + off);
        float part = a.x * wkA.x + a.y * wkA.y + a.z * wkA.z + a.w * wkA.w
                   + e.x * wkE.x + e.y * wkE.y + e.z * wkE.z + e.w * wkE.w
                   + t.x * wkT.x + t.y * wkT.y + t.z * wkT.z + t.w * wkT.w;
        part = half_sum(part);                    // per-half sum, broadcast
        const float p = s_mask[row][n] ? 0.0f : __expf(part + qdot);
        if (sub == 0) s_p[row][n] = p;
        lsum += p;                                // uniform across the half
        oA.x += p * a.x; oA.y += p * a.y; oA.z += p * a.z; oA.w += p * a.w;
        oE.x += p * e.x; oE.y += p * e.y; oE.z += p * e.z; oE.w += p * e.w;
        oT.x += p * t.x; oT.y += p * t.y; oT.z += p * t.z; oT.w += p * t.w;
        off += 2 * DN_;
        n   += 2;
    }

    // ---- combine the two halves of the wave ----
    oA.x += __shfl_xor(oA.x, 32, 64); oA.y += __shfl_xor(oA.y, 32, 64);
    oA.z += __shfl_xor(oA.z, 32, 64); oA.w += __shfl_xor(oA.w, 32, 64);
    oE.x += __shfl_xor(oE.x, 32, 64); oE.y += __shfl_xor(oE.y, 32, 64);
    oE.z += __shfl_xor(oE.z, 32, 64); oE.w += __shfl_xor(oE.w, 32, 64);
    oT.x += __shfl_xor(oT.x, 32, 64); oT.y += __shfl_xor(oT.y, 32, 64);
    oT.z += __shfl_xor(oT.z, 32, 64); oT.w += __shfl_xor(oT.w, 32, 64);
    lsum += __shfl_xor(lsum, 32, 64);
    if (lane == 0) s_red[row][wir] = lsum;
    if (half == 0) {
        *(float4*)&s_oa[wave][c0]            = oA;
        *(float4*)&s_oa[wave][DN_ + c0]      = oE;
        *(float4*)&s_oa[wave][2 * DN_ + c0]  = oT;
    }
    __syncthreads();

    // ---- normalize: attn output vector + attention weights ----
    for (int idx = tid; idx < ROWS * M_; idx += BDIM) {
        const int r = idx / M_, d = idx - r * M_;
        const float Z = s_red[r][0] + s_red[r][1] + s_red[r][2] + s_red[r][3];
        const float invZ = 1.0f / Z;
        s_x[r][d] = (s_oa[4 * r + 0][d] + s_oa[4 * r + 1][d] +
                     s_oa[4 * r + 2][d] + s_oa[4 * r + 3][d]) * invZ;
    }
    for (int idx = tid; idx < ROWS * N_; idx += BDIM) {
        const int r = idx / N_, nn = idx - r * N_;
        const float Z = s_red[r][0] + s_red[r][1] + s_red[r][2] + s_red[r][3];
        attn_out[(blk * ROWS + r) * N_ + nn] = s_p[r][nn] * (1.0f / Z);
    }
    __syncthreads();

    // ---- fc: out2[r][i] = dot(x[r], fc_w[i,:]) + q[r][i]; coalesced W^T stream ----
    if (tid < M_) {
        float acc0 = 0.f, acc1 = 0.f;
#pragma unroll 8
        for (int j = 0; j < M_; ++j) {
            const float w = g_fcT[j * M_ + tid];
            acc0 += s_x[0][j] * w;       // LDS broadcast
            acc1 += s_x[1][j] * w;
        }
        s_y[0][tid] = acc0 + s_q[0][tid];
        s_y[1][tid] = acc1 + s_q[1][tid];
    }
    __syncthreads();

    // ---- layer norm over M (per row: 4 waves) ----
    {
        float ls = 0.f, lq = 0.f;
        for (int j = 64 * wir + lane; j < M_; j += 256) {
            const float v = s_y[row][j];
            ls += v; lq += v * v;
        }
        ls = wave_sum(ls); lq = wave_sum(lq);
        if (lane == 0) { s_red[row][wir] = ls; s_red[row][4 + wir] = lq; }
    }
    __syncthreads();
    for (int idx = tid; idx < ROWS * M_; idx += BDIM) {
        const int r = idx / M_, j = idx - r * M_;
        const float mean = (s_red[r][0] + s_red[r][1] + s_red[r][2] + s_red[r][3]) * (1.0f / M_);
        const float msq  = (s_red[r][4] + s_red[r][5] + s_red[r][6] + s_red[r][7]) * (1.0f / M_);
        const float rstd = rsqrtf(msq - mean * mean + 1e-5f);
        s_y[r][j] = (s_y[r][j] - mean) * rstd * ln_g[j] + ln_b[j];
    }
    for (int idx = tid; idx < ROWS * DN_; idx += BDIM) {
        const int r = idx >> 7, d = idx & 127;
        s_y[r][M_ + d] = s_q[r][d];       // concat src
    }
    __syncthreads();

    // ---- agg fc1: h[r][i] = relu(dot(x512[r], w1[i,:])); thread-per-output ----
    {
        const int r = tid >> 8, i = tid & 255;
        float acc = 0.f;
#pragma unroll 8
        for (int j = 0; j < M_ + DN_; ++j)
            acc += s_y[r][j] * g_w1T[j * 256 + i];
        s_h[r][i] = fmaxf(acc, 0.0f);
    }
    __syncthreads();

    // ---- agg fc2: out[r][i] = dot(h[r], w2[i,:]) ----
    if (tid < 256) {
        const int r = tid >> 7, i = tid & 127;
        float acc = 0.f;
#pragma unroll 8
        for (int j = 0; j < 2 * DN_; ++j)
            acc += s_h[r][j] * g_w2T[j * 128 + i];
        out[(blk * ROWS + r) * DN_ + i] = acc;
    }
}

extern "C" void kernel_launch(void* const* d_in, const int* in_sizes, int n_in,
                              void* d_out, int out_size, void* d_ws, size_t ws_size,
                              hipStream_t stream) {
    const float* src         = (const float*)d_in[0];
    const float* src_t       = (const float*)d_in[1];
    const float* seq         = (const float*)d_in[2];
    const float* seq_t       = (const float*)d_in[3];
    const float* seq_e       = (const float*)d_in[4];
    const int*   mask        = (const int*)  d_in[5];
    const float* shared_attn = (const float*)d_in[6];
    const float* fc_w        = (const float*)d_in[7];
    const float* ln_g        = (const float*)d_in[8];
    const float* ln_b        = (const float*)d_in[9];
    const float* w1          = (const float*)d_in[10];
    const float* w2          = (const float*)d_in[11];

    float* outp     = (float*)d_out;             // (B, DN)
    float* attn_out = (float*)d_out + B_ * DN_;  // (B, N)

    transpose_weights<<<256, 256, 0, stream>>>(fc_w, w1, w2);
    tgnn_kernel<<<B_ / ROWS, BDIM, 0, stream>>>(src, src_t, seq, seq_t, seq_e, mask,
                                                shared_attn, ln_g, ln_b, outp, attn_out);
}

// Round 4
// 356.454 us; speedup vs baseline: 1.3799x; 1.0677x over previous
//
#include <hip/hip_runtime.h>

// TGNN encoder v5 — occupancy to 100%.
// B=1024, N=200, DN=DT=128, M=384.
// v4 post-mortem: all phases latency-exposed; VALU work only ~13us/SIMD but 180us wall.
// 4 waves/SIMD (45% occ, grid-capped) couldn't cover ~2000cy loaded latencies.
// v5: BDIM=1024 (16 waves), ROWS=2, grid=512 -> 2 blocks/CU x 16 waves = 32 waves/CU (100%).
// LDS ~48KB (<80KB for 2 blocks/CU). Target VGPR<=64 (needed for 8 waves/SIMD) — v4's
// main loop compiled to 32 with the same opaque-bound anti-spill pattern.
// GEMV vmem reduction: fc dual-row (384 loads serve 2 rows) + attn_out runs on spare
// threads concurrently; w1 K-split 2-way (256 loads/thread); w2 K-split 4-way (64).
// d_out layout: [ out (1024*128 f32) | attn_w (1024*200 f32) ]

constexpr int B_   = 1024;
constexpr int N_   = 200;
constexpr int DN_  = 128;
constexpr int DT_  = 128;
constexpr int M_   = 384;       // DN + DN + DT
constexpr int BDIM = 1024;      // 16 waves
constexpr int ROWS = 2;         // batch rows per block
constexpr int WPR  = 8;         // waves per row
constexpr int NPW  = N_ / WPR;  // 25 keys per wave
constexpr int ITER = (NPW + 1) / 2;  // 13 pair-iterations (last has a tail)

__device__ float g_fcT[M_ * M_];                 // [j][i] = fc_w[i][j]
__device__ float g_w1T[(M_ + DN_) * (2 * DN_)];  // [j][i] = w1[i][j], j<512, i<256
__device__ float g_w2T[(2 * DN_) * DN_];         // [j][i] = w2[i][j], j<256, i<128

__device__ __forceinline__ float half_sum(float v) {   // sum+broadcast within each 32-lane half
#pragma unroll
    for (int off = 16; off > 0; off >>= 1) v += __shfl_xor(v, off, 64);
    return v;
}
__device__ __forceinline__ float wave_sum(float v) {   // full 64-lane sum+broadcast
#pragma unroll
    for (int off = 32; off > 0; off >>= 1) v += __shfl_xor(v, off, 64);
    return v;
}

__global__ void transpose_weights(const float* __restrict__ fc_w,
                                  const float* __restrict__ w1,
                                  const float* __restrict__ w2) {
    const int stride = gridDim.x * blockDim.x;
    for (int idx = blockIdx.x * blockDim.x + threadIdx.x; idx < M_ * M_; idx += stride) {
        const int j = idx / M_, i = idx - j * M_;
        g_fcT[idx] = fc_w[i * M_ + j];
    }
    for (int idx = blockIdx.x * blockDim.x + threadIdx.x; idx < (M_ + DN_) * (2 * DN_); idx += stride) {
        const int j = idx >> 8, i = idx & 255;
        g_w1T[idx] = w1[i * (M_ + DN_) + j];
    }
    for (int idx = blockIdx.x * blockDim.x + threadIdx.x; idx < (2 * DN_) * DN_; idx += stride) {
        const int j = idx >> 7, i = idx & 127;
        g_w2T[idx] = w2[i * (2 * DN_) + j];
    }
}

__global__ __launch_bounds__(BDIM)
void tgnn_kernel(
    const float* __restrict__ src,      // (B, DN)
    const float* __restrict__ src_t,    // (B, 1, DT)
    const float* __restrict__ seq,      // (B, N, DN)
    const float* __restrict__ seq_t,    // (B, N, DT)
    const float* __restrict__ seq_e,    // (B, N, DN)
    const int*   __restrict__ mask,     // (B, N) int32 (bool)
    const float* __restrict__ shared_attn, // (2M,)
    const float* __restrict__ ln_g,     // (M,)
    const float* __restrict__ ln_b,     // (M,)
    float* __restrict__ out,            // (B, DN)
    float* __restrict__ attn_out)       // (B, N)
{
    const int blk  = blockIdx.x;
    const int tid  = threadIdx.x;
    const int wave = tid >> 6;       // 0..15
    const int lane = tid & 63;
    const int row  = wave >> 3;      // 0/1: which batch row in this block
    const int wir  = wave & 7;       // wave index within row (0..7)
    const int b    = blk * ROWS + row;
    const int half = lane >> 5;      // 0/1: key within pair
    const int sub  = lane & 31;
    const int c0   = 4 * sub;        // element base within a 128-slice

    __shared__ float s_p[ROWS][N_];          // unnormalized exp(score)        1.6 KB
    __shared__ float s_q[ROWS][M_];          // q = [src, 0, src_t]            3   KB
    __shared__ float s_oa[16][M_];           // per-wave weighted-sum partials 24.6KB
    __shared__ float s_x[ROWS][M_];          // normalized attn @ k            3   KB
    __shared__ float s_y[ROWS][M_ + DN_];    // LN output ++ src               4   KB
    __shared__ float s_h[ROWS][2 * DN_];     // relu(x @ w1.T)                 2   KB
    __shared__ int   s_mask[ROWS][N_];       //                                1.6 KB
    __shared__ float s_red[ROWS][16];        // Z partials / LN sums           0.13KB
    __shared__ float s_w1p[2][ROWS][256];    // w1 K-split partials            4   KB
    __shared__ float s_w2p[4][ROWS][128];    // w2 K-split partials            4   KB

    // ---- stage q and mask for both rows (coalesced) ----
    for (int idx = tid; idx < ROWS * M_; idx += BDIM) {
        const int r = idx / M_, d = idx - r * M_;
        const int bb = blk * ROWS + r;
        float v = (d < DN_) ? src[bb * DN_ + d]
                            : (d < 2 * DN_ ? 0.0f : src_t[bb * DT_ + (d - 2 * DN_)]);
        s_q[r][d] = v;
    }
    for (int idx = tid; idx < ROWS * N_; idx += BDIM) {
        const int r = idx / N_, n = idx - r * N_;
        s_mask[r][n] = mask[(blk * ROWS + r) * N_ + n];
    }

    // ---- per-lane weight fragments (global, L2-hot; same for both halves) ----
    const float* wq = shared_attn;
    const float* wk = shared_attn + M_;
    const float4 wkA = *(const float4*)&wk[c0];
    const float4 wkE = *(const float4*)&wk[DN_ + c0];
    const float4 wkT = *(const float4*)&wk[2 * DN_ + c0];
    const float4 wqA = *(const float4*)&wq[c0];
    const float4 wqT = *(const float4*)&wq[2 * DN_ + c0];

    __syncthreads();

    // ---- q-side score (constant over n) ----
    const float4 qa = *(const float4*)&s_q[row][c0];
    const float4 qt = *(const float4*)&s_q[row][2 * DN_ + c0];
    float qp = qa.x * wqA.x + qa.y * wqA.y + qa.z * wqA.z + qa.w * wqA.w
             + qt.x * wqT.x + qt.y * wqT.y + qt.z * wqT.z + qt.w * wqT.w;
    const float qdot = half_sum(qp);

    // ---- fused score + online weighted-sum: 2 keys/iter (one per half-wave) ----
    // Wave handles keys [wir*25, wir*25+25); 13 pair-iters, last has a half-1 tail.
    const int kbase = wir * NPW;
    const float* baseA = seq   + (long)b * (N_ * DN_);
    const float* baseE = seq_e + (long)b * (N_ * DN_);
    const float* baseT = seq_t + (long)b * (N_ * DT_);

    float4 oA = make_float4(0.f, 0.f, 0.f, 0.f);
    float4 oE = oA, oT = oA;
    float lsum = 0.f;

    int iters = ITER;
    asm volatile("" : "+s"(iters));               // opaque bound: no unroll / cross-iter tangle
#pragma unroll 1
    for (int it = 0; it < iters; ++it) {
        const int  ko    = 2 * it + half;
        const bool valid = ko < NPW;              // half=1, it=12 -> key 25 doesn't exist
        const int  n     = kbase + (valid ? ko : NPW - 1);
        const int  off   = n * DN_ + c0;
        const float4 a = *(const float4*)(baseA + off);
        const float4 e = *(const float4*)(baseE + off);
        const float4 t = *(const float4*)(baseT + off);
        float part = a.x * wkA.x + a.y * wkA.y + a.z * wkA.z + a.w * wkA.w
                   + e.x * wkE.x + e.y * wkE.y + e.z * wkE.z + e.w * wkE.w
                   + t.x * wkT.x + t.y * wkT.y + t.z * wkT.z + t.w * wkT.w;
        part = half_sum(part);                    // per-half sum, broadcast
        const float p = (valid && !s_mask[row][n]) ? __expf(part + qdot) : 0.0f;
        if (sub == 0 && valid) s_p[row][n] = p;
        lsum += p;                                // uniform across the half
        oA.x += p * a.x; oA.y += p * a.y; oA.z += p * a.z; oA.w += p * a.w;
        oE.x += p * e.x; oE.y += p * e.y; oE.z += p * e.z; oE.w += p * e.w;
        oT.x += p * t.x; oT.y += p * t.y; oT.z += p * t.z; oT.w += p * t.w;
    }

    // ---- combine the two halves of the wave ----
    oA.x += __shfl_xor(oA.x, 32, 64); oA.y += __shfl_xor(oA.y, 32, 64);
    oA.z += __shfl_xor(oA.z, 32, 64); oA.w += __shfl_xor(oA.w, 32, 64);
    oE.x += __shfl_xor(oE.x, 32, 64); oE.y += __shfl_xor(oE.y, 32, 64);
    oE.z += __shfl_xor(oE.z, 32, 64); oE.w += __shfl_xor(oE.w, 32, 64);
    oT.x += __shfl_xor(oT.x, 32, 64); oT.y += __shfl_xor(oT.y, 32, 64);
    oT.z += __shfl_xor(oT.z, 32, 64); oT.w += __shfl_xor(oT.w, 32, 64);
    lsum += __shfl_xor(lsum, 32, 64);
    if (lane == 0) s_red[row][wir] = lsum;
    if (half == 0) {
        *(float4*)&s_oa[wave][c0]            = oA;
        *(float4*)&s_oa[wave][DN_ + c0]      = oE;
        *(float4*)&s_oa[wave][2 * DN_ + c0]  = oT;
    }
    __syncthreads();

    // ---- normalize: attn output vector (8 wave-partials per row) ----
    for (int idx = tid; idx < ROWS * M_; idx += BDIM) {
        const int r = idx / M_, d = idx - r * M_;
        const float Z = s_red[r][0] + s_red[r][1] + s_red[r][2] + s_red[r][3]
                      + s_red[r][4] + s_red[r][5] + s_red[r][6] + s_red[r][7];
        const float invZ = 1.0f / Z;
        float acc = 0.f;
#pragma unroll
        for (int w = 0; w < 8; ++w) acc += s_oa[8 * r + w][d];
        s_x[r][d] = acc * invZ;
    }
    __syncthreads();

    // ---- fc (dual-row, threads 0..383) || attn_out (threads 384..639) ----
    if (tid < M_) {
        float acc0 = 0.f, acc1 = 0.f;
#pragma unroll 8
        for (int j = 0; j < M_; ++j) {
            const float w = g_fcT[j * M_ + tid];
            acc0 += s_x[0][j] * w;       // LDS broadcast
            acc1 += s_x[1][j] * w;
        }
        s_y[0][tid] = acc0 + s_q[0][tid];
        s_y[1][tid] = acc1 + s_q[1][tid];
    } else if (tid < M_ + 256) {
        const int t2 = tid - M_;
        for (int idx = t2; idx < ROWS * N_; idx += 256) {
            const int r = idx / N_, nn = idx - r * N_;
            const float Z = s_red[r][0] + s_red[r][1] + s_red[r][2] + s_red[r][3]
                          + s_red[r][4] + s_red[r][5] + s_red[r][6] + s_red[r][7];
            attn_out[(blk * ROWS + r) * N_ + nn] = s_p[r][nn] * (1.0f / Z);
        }
    }
    __syncthreads();

    // ---- layer norm over M (per row: 8 waves; waves 6,7 contribute zero) ----
    {
        float ls = 0.f, lq = 0.f;
        for (int j = 64 * wir + lane; j < M_; j += 512) {
            const float v = s_y[row][j];
            ls += v; lq += v * v;
        }
        ls = wave_sum(ls); lq = wave_sum(lq);
        if (lane == 0) { s_red[row][wir] = ls; s_red[row][8 + wir] = lq; }
    }
    __syncthreads();
    for (int idx = tid; idx < ROWS * M_; idx += BDIM) {
        const int r = idx / M_, j = idx - r * M_;
        float sm = 0.f, sq2 = 0.f;
#pragma unroll
        for (int w = 0; w < 8; ++w) { sm += s_red[r][w]; sq2 += s_red[r][8 + w]; }
        const float mean = sm * (1.0f / M_);
        const float msq  = sq2 * (1.0f / M_);
        const float rstd = rsqrtf(msq - mean * mean + 1e-5f);
        s_y[r][j] = (s_y[r][j] - mean) * rstd * ln_g[j] + ln_b[j];
    }
    for (int idx = tid; idx < ROWS * DN_; idx += BDIM) {
        const int r = idx >> 7, d = idx & 127;
        s_y[r][M_ + d] = s_q[r][d];       // concat src
    }
    __syncthreads();

    // ---- agg fc1: dual-row, K-split 2-way. jobs: kk(2) x i(256), threads 0..511 ----
    if (tid < 512) {
        const int kk = tid >> 8, i = tid & 255;
        const int j0 = kk * 256;
        float acc0 = 0.f, acc1 = 0.f;
#pragma unroll 8
        for (int j = j0; j < j0 + 256; ++j) {
            const float w = g_w1T[j * 256 + i];
            acc0 += s_y[0][j] * w;
            acc1 += s_y[1][j] * w;
        }
        s_w1p[kk][0][i] = acc0;
        s_w1p[kk][1][i] = acc1;
    }
    __syncthreads();
    if (tid < 512) {
        const int r = tid >> 8, i = tid & 255;
        s_h[r][i] = fmaxf(s_w1p[0][r][i] + s_w1p[1][r][i], 0.0f);
    }
    __syncthreads();

    // ---- agg fc2: dual-row, K-split 4-way. jobs: kk(4) x i(128), threads 0..511 ----
    if (tid < 512) {
        const int kk = tid >> 7, i = tid & 127;
        const int j0 = kk * 64;
        float acc0 = 0.f, acc1 = 0.f;
#pragma unroll 8
        for (int j = j0; j < j0 + 64; ++j) {
            const float w = g_w2T[j * 128 + i];
            acc0 += s_h[0][j] * w;
            acc1 += s_h[1][j] * w;
        }
        s_w2p[kk][0][i] = acc0;
        s_w2p[kk][1][i] = acc1;
    }
    __syncthreads();
    if (tid < 256) {
        const int r = tid >> 7, i = tid & 127;
        out[(blk * ROWS + r) * DN_ + i] =
            s_w2p[0][r][i] + s_w2p[1][r][i] + s_w2p[2][r][i] + s_w2p[3][r][i];
    }
}

extern "C" void kernel_launch(void* const* d_in, const int* in_sizes, int n_in,
                              void* d_out, int out_size, void* d_ws, size_t ws_size,
                              hipStream_t stream) {
    const float* src         = (const float*)d_in[0];
    const float* src_t       = (const float*)d_in[1];
    const float* seq         = (const float*)d_in[2];
    const float* seq_t       = (const float*)d_in[3];
    const float* seq_e       = (const float*)d_in[4];
    const int*   mask        = (const int*)  d_in[5];
    const float* shared_attn = (const float*)d_in[6];
    const float* fc_w        = (const float*)d_in[7];
    const float* ln_g        = (const float*)d_in[8];
    const float* ln_b        = (const float*)d_in[9];
    const float* w1          = (const float*)d_in[10];
    const float* w2          = (const float*)d_in[11];

    float* outp     = (float*)d_out;             // (B, DN)
    float* attn_out = (float*)d_out + B_ * DN_;  // (B, N)

    transpose_weights<<<256, 256, 0, stream>>>(fc_w, w1, w2);
    tgnn_kernel<<<B_ / ROWS, BDIM, 0, stream>>>(src, src_t, seq, seq_t, seq_e, mask,
                                                shared_attn, ln_g, ln_b, outp, attn_out);
}

// Round 5
// 341.086 us; speedup vs baseline: 1.4421x; 1.0451x over previous
//
#include <hip/hip_runtime.h>

// TGNN encoder v6 — cut dependent-latency windows; pipeline the rest.
// B=1024, N=200, DN=DT=128, M=384.
// v5 post-mortem: wall ~= (#serial load-windows) x (loaded latency ~1-2K cy);
// occupancy alone can't shrink it (phase-locked waves stall together).
// v5 windows/thread: main 13 + fc 48 + w1 32 + w2 8 = 101.
// v6: fc K-split2 x unroll16 -> 12; w1 K-split4 x unroll16 -> 8; w2 K-split8 -> 2;
// main loop depth-1 prefetch (next window's loads fly under shfl/exp chain).
// Register budget: cur12+next12+acc12+wk12+misc ~58 < 64 (keeps 8 waves/SIMD tier).
// Grid 512 x 1024 threads, ROWS=2, 2 blocks/CU, LDS ~62KB (<80KB/block for 2/CU).
// d_out layout: [ out (1024*128 f32) | attn_w (1024*200 f32) ]

constexpr int B_   = 1024;
constexpr int N_   = 200;
constexpr int DN_  = 128;
constexpr int DT_  = 128;
constexpr int M_   = 384;       // DN + DN + DT
constexpr int BDIM = 1024;      // 16 waves
constexpr int ROWS = 2;         // batch rows per block
constexpr int WPR  = 8;         // waves per row
constexpr int NPW  = N_ / WPR;  // 25 keys per wave
constexpr int ITER = (NPW + 1) / 2;  // 13 pair-iterations (last has a half-1 tail)

__device__ float g_fcT[M_ * M_];                 // [j][i] = fc_w[i][j]
__device__ float g_w1T[(M_ + DN_) * (2 * DN_)];  // [j][i] = w1[i][j], j<512, i<256
__device__ float g_w2T[(2 * DN_) * DN_];         // [j][i] = w2[i][j], j<256, i<128

__device__ __forceinline__ float half_sum(float v) {   // sum+broadcast within each 32-lane half
#pragma unroll
    for (int off = 16; off > 0; off >>= 1) v += __shfl_xor(v, off, 64);
    return v;
}
__device__ __forceinline__ float wave_sum(float v) {   // full 64-lane sum+broadcast
#pragma unroll
    for (int off = 32; off > 0; off >>= 1) v += __shfl_xor(v, off, 64);
    return v;
}

__global__ void transpose_weights(const float* __restrict__ fc_w,
                                  const float* __restrict__ w1,
                                  const float* __restrict__ w2) {
    const int stride = gridDim.x * blockDim.x;
    for (int idx = blockIdx.x * blockDim.x + threadIdx.x; idx < M_ * M_; idx += stride) {
        const int j = idx / M_, i = idx - j * M_;
        g_fcT[idx] = fc_w[i * M_ + j];
    }
    for (int idx = blockIdx.x * blockDim.x + threadIdx.x; idx < (M_ + DN_) * (2 * DN_); idx += stride) {
        const int j = idx >> 8, i = idx & 255;
        g_w1T[idx] = w1[i * (M_ + DN_) + j];
    }
    for (int idx = blockIdx.x * blockDim.x + threadIdx.x; idx < (2 * DN_) * DN_; idx += stride) {
        const int j = idx >> 7, i = idx & 127;
        g_w2T[idx] = w2[i * (2 * DN_) + j];
    }
}

__global__ __launch_bounds__(BDIM)
void tgnn_kernel(
    const float* __restrict__ src,      // (B, DN)
    const float* __restrict__ src_t,    // (B, 1, DT)
    const float* __restrict__ seq,      // (B, N, DN)
    const float* __restrict__ seq_t,    // (B, N, DT)
    const float* __restrict__ seq_e,    // (B, N, DN)
    const int*   __restrict__ mask,     // (B, N) int32 (bool)
    const float* __restrict__ shared_attn, // (2M,)
    const float* __restrict__ ln_g,     // (M,)
    const float* __restrict__ ln_b,     // (M,)
    float* __restrict__ out,            // (B, DN)
    float* __restrict__ attn_out)       // (B, N)
{
    const int blk  = blockIdx.x;
    const int tid  = threadIdx.x;
    const int wave = tid >> 6;       // 0..15
    const int lane = tid & 63;
    const int row  = wave >> 3;      // 0/1: which batch row in this block
    const int wir  = wave & 7;       // wave index within row (0..7)
    const int b    = blk * ROWS + row;
    const int half = lane >> 5;      // 0/1: key within pair
    const int sub  = lane & 31;
    const int c0   = 4 * sub;        // element base within a 128-slice

    __shared__ float s_p[ROWS][N_];          // unnormalized exp(score)        1.6 KB
    __shared__ float s_q[ROWS][M_];          // q = [src, 0, src_t]            3   KB
    __shared__ float s_oa[16][M_];           // per-wave weighted-sum partials 24.6KB
    __shared__ float s_x[ROWS][M_];          // normalized attn @ k            3   KB
    __shared__ float s_y[ROWS][M_ + DN_];    // LN output ++ src               4   KB
    __shared__ float s_h[ROWS][2 * DN_];     // relu(x @ w1.T)                 2   KB
    __shared__ int   s_mask[ROWS][N_];       //                                1.6 KB
    __shared__ float s_red[ROWS][16];        // Z partials / LN sums           0.13KB
    __shared__ float s_fcp[2][ROWS][M_];     // fc K-split partials            6   KB
    __shared__ float s_w1p[4][ROWS][256];    // w1 K-split partials            8   KB
    __shared__ float s_w2p[8][ROWS][128];    // w2 K-split partials            8   KB

    // ---- stage q and mask for both rows (coalesced) ----
    for (int idx = tid; idx < ROWS * M_; idx += BDIM) {
        const int r = idx / M_, d = idx - r * M_;
        const int bb = blk * ROWS + r;
        float v = (d < DN_) ? src[bb * DN_ + d]
                            : (d < 2 * DN_ ? 0.0f : src_t[bb * DT_ + (d - 2 * DN_)]);
        s_q[r][d] = v;
    }
    for (int idx = tid; idx < ROWS * N_; idx += BDIM) {
        const int r = idx / N_, n = idx - r * N_;
        s_mask[r][n] = mask[(blk * ROWS + r) * N_ + n];
    }

    // ---- per-lane weight fragments (global, L2-hot; same for both halves) ----
    const float* wq = shared_attn;
    const float* wk = shared_attn + M_;
    const float4 wkA = *(const float4*)&wk[c0];
    const float4 wkE = *(const float4*)&wk[DN_ + c0];
    const float4 wkT = *(const float4*)&wk[2 * DN_ + c0];
    const float4 wqA = *(const float4*)&wq[c0];
    const float4 wqT = *(const float4*)&wq[2 * DN_ + c0];

    __syncthreads();

    // ---- q-side score (constant over n) ----
    const float4 qa = *(const float4*)&s_q[row][c0];
    const float4 qt = *(const float4*)&s_q[row][2 * DN_ + c0];
    float qp = qa.x * wqA.x + qa.y * wqA.y + qa.z * wqA.z + qa.w * wqA.w
             + qt.x * wqT.x + qt.y * wqT.y + qt.z * wqT.z + qt.w * wqT.w;
    const float qdot = half_sum(qp);

    // ---- fused score + online weighted-sum, depth-1 prefetch ----
    // Wave handles keys [wir*25, wir*25+25); 13 pair-iters, last has a half-1 tail.
    const int kbase = wir * NPW;
    const float* baseA = seq   + (long)b * (N_ * DN_);
    const float* baseE = seq_e + (long)b * (N_ * DN_);
    const float* baseT = seq_t + (long)b * (N_ * DT_);

    float4 oA = make_float4(0.f, 0.f, 0.f, 0.f);
    float4 oE = oA, oT = oA;
    float lsum = 0.f;

    // preload window 0 (it=0 is always valid for both halves)
    {
        const int off0 = (kbase + half) * DN_ + c0;
        // fallthrough into loop with cur = window 0
        float4 a = *(const float4*)(baseA + off0);
        float4 e = *(const float4*)(baseE + off0);
        float4 t = *(const float4*)(baseT + off0);

        int iters = ITER;
        asm volatile("" : "+s"(iters));           // opaque bound: no unroll
#pragma unroll 1
        for (int it = 0; it < iters; ++it) {
            // current window's key
            const int  ko_c  = 2 * it + half;
            const bool val_c = ko_c < NPW;
            const int  n_c   = kbase + (val_c ? ko_c : NPW - 1);
            // issue next window's loads (clamped at the end)
            const int  itn   = (it + 1 < ITER) ? it + 1 : it;
            const int  ko_n  = 2 * itn + half;
            const int  n_n   = kbase + ((ko_n < NPW) ? ko_n : NPW - 1);
            const int  off_n = n_n * DN_ + c0;
            const float4 an = *(const float4*)(baseA + off_n);
            const float4 en = *(const float4*)(baseE + off_n);
            const float4 tn = *(const float4*)(baseT + off_n);
            // compute with current window while next flies
            float part = a.x * wkA.x + a.y * wkA.y + a.z * wkA.z + a.w * wkA.w
                       + e.x * wkE.x + e.y * wkE.y + e.z * wkE.z + e.w * wkE.w
                       + t.x * wkT.x + t.y * wkT.y + t.z * wkT.z + t.w * wkT.w;
            part = half_sum(part);                // per-half sum, broadcast
            const float p = (val_c && !s_mask[row][n_c]) ? __expf(part + qdot) : 0.0f;
            if (sub == 0 && val_c) s_p[row][n_c] = p;
            lsum += p;                            // uniform across the half
            oA.x += p * a.x; oA.y += p * a.y; oA.z += p * a.z; oA.w += p * a.w;
            oE.x += p * e.x; oE.y += p * e.y; oE.z += p * e.z; oE.w += p * e.w;
            oT.x += p * t.x; oT.y += p * t.y; oT.z += p * t.z; oT.w += p * t.w;
            a = an; e = en; t = tn;
        }
    }

    // ---- combine the two halves of the wave ----
    oA.x += __shfl_xor(oA.x, 32, 64); oA.y += __shfl_xor(oA.y, 32, 64);
    oA.z += __shfl_xor(oA.z, 32, 64); oA.w += __shfl_xor(oA.w, 32, 64);
    oE.x += __shfl_xor(oE.x, 32, 64); oE.y += __shfl_xor(oE.y, 32, 64);
    oE.z += __shfl_xor(oE.z, 32, 64); oE.w += __shfl_xor(oE.w, 32, 64);
    oT.x += __shfl_xor(oT.x, 32, 64); oT.y += __shfl_xor(oT.y, 32, 64);
    oT.z += __shfl_xor(oT.z, 32, 64); oT.w += __shfl_xor(oT.w, 32, 64);
    lsum += __shfl_xor(lsum, 32, 64);
    if (lane == 0) s_red[row][wir] = lsum;
    if (half == 0) {
        *(float4*)&s_oa[wave][c0]            = oA;
        *(float4*)&s_oa[wave][DN_ + c0]      = oE;
        *(float4*)&s_oa[wave][2 * DN_ + c0]  = oT;
    }
    __syncthreads();

    // ---- normalize: attn output vector + attention weights (all threads) ----
    for (int idx = tid; idx < ROWS * M_; idx += BDIM) {
        const int r = idx / M_, d = idx - r * M_;
        const float Z = s_red[r][0] + s_red[r][1] + s_red[r][2] + s_red[r][3]
                      + s_red[r][4] + s_red[r][5] + s_red[r][6] + s_red[r][7];
        const float invZ = 1.0f / Z;
        float acc = 0.f;
#pragma unroll
        for (int w = 0; w < 8; ++w) acc += s_oa[8 * r + w][d];
        s_x[r][d] = acc * invZ;
    }
    for (int idx = tid; idx < ROWS * N_; idx += BDIM) {
        const int r = idx / N_, nn = idx - r * N_;
        const float Z = s_red[r][0] + s_red[r][1] + s_red[r][2] + s_red[r][3]
                      + s_red[r][4] + s_red[r][5] + s_red[r][6] + s_red[r][7];
        attn_out[(blk * ROWS + r) * N_ + nn] = s_p[r][nn] * (1.0f / Z);
    }
    __syncthreads();

    // ---- fc: dual-row, K-split 2-way, unroll 16 -> 12 windows (768 threads) ----
    if (tid < 2 * M_) {
        const int kk = (tid >= M_) ? 1 : 0;
        const int i  = tid - kk * M_;
        const int j0 = kk * (M_ / 2);
        float acc0 = 0.f, acc1 = 0.f;
#pragma unroll 16
        for (int j = j0; j < j0 + M_ / 2; ++j) {
            const float w = g_fcT[j * M_ + i];
            acc0 += s_x[0][j] * w;       // LDS broadcast
            acc1 += s_x[1][j] * w;
        }
        s_fcp[kk][0][i] = acc0;
        s_fcp[kk][1][i] = acc1;
    }
    __syncthreads();
    for (int idx = tid; idx < ROWS * M_; idx += BDIM) {
        const int r = idx / M_, i = idx - r * M_;
        s_y[r][i] = s_fcp[0][r][i] + s_fcp[1][r][i] + s_q[r][i];
    }
    __syncthreads();

    // ---- layer norm over M (per row: 8 waves) ----
    {
        float ls = 0.f, lq = 0.f;
        for (int j = 64 * wir + lane; j < M_; j += 512) {
            const float v = s_y[row][j];
            ls += v; lq += v * v;
        }
        ls = wave_sum(ls); lq = wave_sum(lq);
        if (lane == 0) { s_red[row][wir] = ls; s_red[row][8 + wir] = lq; }
    }
    __syncthreads();
    for (int idx = tid; idx < ROWS * M_; idx += BDIM) {
        const int r = idx / M_, j = idx - r * M_;
        float sm = 0.f, sq2 = 0.f;
#pragma unroll
        for (int w = 0; w < 8; ++w) { sm += s_red[r][w]; sq2 += s_red[r][8 + w]; }
        const float mean = sm * (1.0f / M_);
        const float msq  = sq2 * (1.0f / M_);
        const float rstd = rsqrtf(msq - mean * mean + 1e-5f);
        s_y[r][j] = (s_y[r][j] - mean) * rstd * ln_g[j] + ln_b[j];
    }
    for (int idx = tid; idx < ROWS * DN_; idx += BDIM) {
        const int r = idx >> 7, d = idx & 127;
        s_y[r][M_ + d] = s_q[r][d];       // concat src
    }
    __syncthreads();

    // ---- agg fc1: dual-row, K-split 4-way, unroll 16 -> 8 windows (1024 threads) ----
    {
        const int kk = tid >> 8, i = tid & 255;
        const int j0 = kk * 128;
        float acc0 = 0.f, acc1 = 0.f;
#pragma unroll 16
        for (int j = j0; j < j0 + 128; ++j) {
            const float w = g_w1T[j * 256 + i];
            acc0 += s_y[0][j] * w;
            acc1 += s_y[1][j] * w;
        }
        s_w1p[kk][0][i] = acc0;
        s_w1p[kk][1][i] = acc1;
    }
    __syncthreads();
    if (tid < 512) {
        const int r = tid >> 8, i = tid & 255;
        s_h[r][i] = fmaxf(s_w1p[0][r][i] + s_w1p[1][r][i] +
                          s_w1p[2][r][i] + s_w1p[3][r][i], 0.0f);
    }
    __syncthreads();

    // ---- agg fc2: dual-row, K-split 8-way, unroll 16 -> 2 windows (1024 threads) ----
    {
        const int kk = tid >> 7, i = tid & 127;
        const int j0 = kk * 32;
        float acc0 = 0.f, acc1 = 0.f;
#pragma unroll 16
        for (int j = j0; j < j0 + 32; ++j) {
            const float w = g_w2T[j * 128 + i];
            acc0 += s_h[0][j] * w;
            acc1 += s_h[1][j] * w;
        }
        s_w2p[kk][0][i] = acc0;
        s_w2p[kk][1][i] = acc1;
    }
    __syncthreads();
    if (tid < 256) {
        const int r = tid >> 7, i = tid & 127;
        float v = 0.f;
#pragma unroll
        for (int kk = 0; kk < 8; ++kk) v += s_w2p[kk][r][i];
        out[(blk * ROWS + r) * DN_ + i] = v;
    }
}

extern "C" void kernel_launch(void* const* d_in, const int* in_sizes, int n_in,
                              void* d_out, int out_size, void* d_ws, size_t ws_size,
                              hipStream_t stream) {
    const float* src         = (const float*)d_in[0];
    const float* src_t       = (const float*)d_in[1];
    const float* seq         = (const float*)d_in[2];
    const float* seq_t       = (const float*)d_in[3];
    const float* seq_e       = (const float*)d_in[4];
    const int*   mask        = (const int*)  d_in[5];
    const float* shared_attn = (const float*)d_in[6];
    const float* fc_w        = (const float*)d_in[7];
    const float* ln_g        = (const float*)d_in[8];
    const float* ln_b        = (const float*)d_in[9];
    const float* w1          = (const float*)d_in[10];
    const float* w2          = (const float*)d_in[11];

    float* outp     = (float*)d_out;             // (B, DN)
    float* attn_out = (float*)d_out + B_ * DN_;  // (B, N)

    transpose_weights<<<256, 256, 0, stream>>>(fc_w, w1, w2);
    tgnn_kernel<<<B_ / ROWS, BDIM, 0, stream>>>(src, src_t, seq, seq_t, seq_e, mask,
                                                shared_attn, ln_g, ln_b, outp, attn_out);
}